// Round 1
// baseline (630.247 us; speedup 1.0000x reference)
//
#include <hip/hip_runtime.h>

#define N_NODES 100000
#define E_EDGES 600000
#define LATDIM 128
#define HEAD 4
#define HDIM 32

// ---------------------------------------------------------------------------
// Kernel A: fused per-node Q/K/V transform.  out = embeds @ W for 3 weights.
// Block: 256 threads, tile: 64 rows x 128 cols, micro-tile 8 rows x 4 cols.
// LDS stages the 64x128 embeds tile once, reused for all 3 weight matrices.
// ---------------------------------------------------------------------------
__global__ __launch_bounds__(256) void qkv_kernel(
    const float* __restrict__ embeds,
    const float* __restrict__ qT,
    const float* __restrict__ kT,
    const float* __restrict__ vT,
    float* __restrict__ Q, float* __restrict__ K, float* __restrict__ V)
{
    __shared__ float smem[64][128];   // 32 KiB
    const int rowBase = blockIdx.x * 64;
    const int tid = threadIdx.x;

    // Stage 64 rows of embeds (float4 loads, coalesced). Tail rows -> 0.
    for (int i = tid; i < 64 * 32; i += 256) {   // 2048 float4
        int r  = i >> 5;          // row in tile
        int c4 = i & 31;          // float4 index in row
        int gr = rowBase + r;
        float4 val = make_float4(0.f, 0.f, 0.f, 0.f);
        if (gr < N_NODES) val = ((const float4*)embeds)[gr * 32 + c4];
        ((float4*)&smem[r][0])[c4] = val;
    }
    __syncthreads();

    const int cg = tid & 31;      // col group: cols cg*4 .. cg*4+3
    const int rg = tid >> 5;      // row group: rows rg*8 .. rg*8+7

    const float* Ws[3]   = {qT, kT, vT};
    float*       Outs[3] = {Q, K, V};

    for (int w = 0; w < 3; ++w) {
        const float* __restrict__ W = Ws[w];
        float acc[8][4];
        #pragma unroll
        for (int i = 0; i < 8; ++i)
            #pragma unroll
            for (int j = 0; j < 4; ++j) acc[i][j] = 0.f;

        for (int k = 0; k < 128; ++k) {
            // lanes 0..31 load 128 consecutive floats -> 512B coalesced
            float4 wv = ((const float4*)(W + k * 128))[cg];
            #pragma unroll
            for (int i = 0; i < 8; ++i) {
                float e = smem[rg * 8 + i][k];   // broadcast within half-wave
                acc[i][0] += e * wv.x;
                acc[i][1] += e * wv.y;
                acc[i][2] += e * wv.z;
                acc[i][3] += e * wv.w;
            }
        }

        float* __restrict__ O = Outs[w];
        #pragma unroll
        for (int i = 0; i < 8; ++i) {
            int gr = rowBase + rg * 8 + i;
            if (gr < N_NODES) {
                float4 v4 = make_float4(acc[i][0], acc[i][1], acc[i][2], acc[i][3]);
                ((float4*)(O + gr * 128))[cg] = v4;
            }
        }
    }
}

// ---------------------------------------------------------------------------
// Kernel B: per-(edge, head) attention logit -> expAtt, atomic norm.
// ---------------------------------------------------------------------------
__global__ __launch_bounds__(256) void att_kernel(
    const float* __restrict__ Q, const float* __restrict__ K,
    const float* __restrict__ filt,
    const int* __restrict__ rows, const int* __restrict__ cols,
    float* __restrict__ expAtt, float* __restrict__ norm)
{
    int t = blockIdx.x * 256 + threadIdx.x;
    int e = t >> 2;          // t / HEAD
    int h = t & 3;           // t % HEAD
    if (e >= E_EDGES) return;
    int r = rows[e];
    int c = cols[e];

    const float4* q4 = (const float4*)(Q + (size_t)r * 128 + h * 32);
    const float4* k4 = (const float4*)(K + (size_t)c * 128 + h * 32);
    float dot = 0.f;
    #pragma unroll
    for (int i = 0; i < 8; ++i) {
        float4 a = q4[i];
        float4 b = k4[i];
        dot += a.x * b.x + a.y * b.y + a.z * b.z + a.w * b.w;
    }
    dot = fminf(fmaxf(dot, -10.f), 10.f) + filt[(size_t)c * HEAD + h];
    float ex = __expf(dot);
    expAtt[(size_t)e * HEAD + h] = ex;
    atomicAdd(&norm[(size_t)r * HEAD + h], ex);
}

// ---------------------------------------------------------------------------
// Kernel C: per-(edge, dim) weighted scatter-add into out[row].
// ---------------------------------------------------------------------------
__global__ __launch_bounds__(256) void agg_kernel(
    const float* __restrict__ V, const float* __restrict__ expAtt,
    const float* __restrict__ norm,
    const int* __restrict__ rows, const int* __restrict__ cols,
    float* __restrict__ out)
{
    long long t = (long long)blockIdx.x * 256 + threadIdx.x;
    int e = (int)(t >> 7);        // t / 128
    int d = (int)(t & 127);       // dim
    if (e >= E_EDGES) return;
    int r = rows[e];
    int c = cols[e];
    int h = d >> 5;               // head

    float w = expAtt[(size_t)e * HEAD + h] /
              (norm[(size_t)r * HEAD + h] + 1e-8f);
    float val = w * V[(size_t)c * 128 + d];
    atomicAdd(&out[(size_t)r * 128 + d], val);
}

// ---------------------------------------------------------------------------
extern "C" void kernel_launch(void* const* d_in, const int* in_sizes, int n_in,
                              void* d_out, int out_size, void* d_ws, size_t ws_size,
                              hipStream_t stream) {
    const float* embeds = (const float*)d_in[0];
    const float* qT     = (const float*)d_in[1];
    const float* kT     = (const float*)d_in[2];
    const float* vT     = (const float*)d_in[3];
    const float* filt   = (const float*)d_in[4];
    const int*   rows   = (const int*)d_in[5];
    const int*   cols   = (const int*)d_in[6];
    float*       out    = (float*)d_out;

    // Workspace layout (all float32):
    //   Q: N*128 | K: N*128 | V: N*128 | expAtt: E*4 | norm: N*4
    float* Q      = (float*)d_ws;
    float* K      = Q + (size_t)N_NODES * 128;
    float* V      = K + (size_t)N_NODES * 128;
    float* expAtt = V + (size_t)N_NODES * 128;
    float* norm   = expAtt + (size_t)E_EDGES * HEAD;

    hipMemsetAsync(out,  0, sizeof(float) * (size_t)N_NODES * 128, stream);
    hipMemsetAsync(norm, 0, sizeof(float) * (size_t)N_NODES * HEAD, stream);

    qkv_kernel<<<(N_NODES + 63) / 64, 256, 0, stream>>>(embeds, qT, kT, vT, Q, K, V);

    att_kernel<<<(E_EDGES * HEAD + 255) / 256, 256, 0, stream>>>(
        Q, K, filt, rows, cols, expAtt, norm);

    long long aggThreads = (long long)E_EDGES * 128;
    agg_kernel<<<(int)((aggThreads + 255) / 256), 256, 0, stream>>>(
        V, expAtt, norm, rows, cols, out);
}

// Round 2
// 606.756 us; speedup vs baseline: 1.0387x; 1.0387x over previous
//
#include <hip/hip_runtime.h>

#define N_NODES 100000
#define E_EDGES 600000
#define LATDIM 128
#define HEAD 4
#define HDIM 32

#define SCAN_CHUNK 1024                       // elements per scan1 block
#define SCAN_NB ((N_NODES + SCAN_CHUNK - 1) / SCAN_CHUNK)   // 98

// ---------------------------------------------------------------------------
// Kernel A: fused per-node Q/K/V transform.  out = embeds @ W for 3 weights.
// ---------------------------------------------------------------------------
__global__ __launch_bounds__(256) void qkv_kernel(
    const float* __restrict__ embeds,
    const float* __restrict__ qT,
    const float* __restrict__ kT,
    const float* __restrict__ vT,
    float* __restrict__ Q, float* __restrict__ K, float* __restrict__ V)
{
    __shared__ float smem[64][128];   // 32 KiB
    const int rowBase = blockIdx.x * 64;
    const int tid = threadIdx.x;

    for (int i = tid; i < 64 * 32; i += 256) {   // 2048 float4
        int r  = i >> 5;
        int c4 = i & 31;
        int gr = rowBase + r;
        float4 val = make_float4(0.f, 0.f, 0.f, 0.f);
        if (gr < N_NODES) val = ((const float4*)embeds)[gr * 32 + c4];
        ((float4*)&smem[r][0])[c4] = val;
    }
    __syncthreads();

    const int cg = tid & 31;
    const int rg = tid >> 5;

    const float* Ws[3]   = {qT, kT, vT};
    float*       Outs[3] = {Q, K, V};

    for (int w = 0; w < 3; ++w) {
        const float* __restrict__ W = Ws[w];
        float acc[8][4];
        #pragma unroll
        for (int i = 0; i < 8; ++i)
            #pragma unroll
            for (int j = 0; j < 4; ++j) acc[i][j] = 0.f;

        for (int k = 0; k < 128; ++k) {
            float4 wv = ((const float4*)(W + k * 128))[cg];
            #pragma unroll
            for (int i = 0; i < 8; ++i) {
                float e = smem[rg * 8 + i][k];
                acc[i][0] += e * wv.x;
                acc[i][1] += e * wv.y;
                acc[i][2] += e * wv.z;
                acc[i][3] += e * wv.w;
            }
        }

        float* __restrict__ O = Outs[w];
        #pragma unroll
        for (int i = 0; i < 8; ++i) {
            int gr = rowBase + rg * 8 + i;
            if (gr < N_NODES) {
                float4 v4 = make_float4(acc[i][0], acc[i][1], acc[i][2], acc[i][3]);
                ((float4*)(O + gr * 128))[cg] = v4;
            }
        }
    }
}

// ---------------------------------------------------------------------------
// Kernel B: per-(edge, head) attention logit -> expAtt (no norm atomic).
// ---------------------------------------------------------------------------
__global__ __launch_bounds__(256) void att_kernel(
    const float* __restrict__ Q, const float* __restrict__ K,
    const float* __restrict__ filt,
    const int* __restrict__ rows, const int* __restrict__ cols,
    float* __restrict__ expAtt)
{
    int t = blockIdx.x * 256 + threadIdx.x;
    int e = t >> 2;
    int h = t & 3;
    if (e >= E_EDGES) return;
    int r = rows[e];
    int c = cols[e];

    const float4* q4 = (const float4*)(Q + (size_t)r * 128 + h * 32);
    const float4* k4 = (const float4*)(K + (size_t)c * 128 + h * 32);
    float dot = 0.f;
    #pragma unroll
    for (int i = 0; i < 8; ++i) {
        float4 a = q4[i];
        float4 b = k4[i];
        dot += a.x * b.x + a.y * b.y + a.z * b.z + a.w * b.w;
    }
    dot = fminf(fmaxf(dot, -10.f), 10.f) + filt[(size_t)c * HEAD + h];
    expAtt[(size_t)e * HEAD + h] = __expf(dot);
}

// ---------------------------------------------------------------------------
// CSR build: histogram -> exclusive scan -> scatter
// ---------------------------------------------------------------------------
__global__ __launch_bounds__(256) void hist_kernel(
    const int* __restrict__ rows, int* __restrict__ counts)
{
    int e = blockIdx.x * 256 + threadIdx.x;
    if (e < E_EDGES) atomicAdd(&counts[rows[e]], 1);
}

// scan1: per-1024-chunk exclusive scan, emit chunk totals
__global__ __launch_bounds__(256) void scan1_kernel(
    const int* __restrict__ counts, int* __restrict__ starts,
    int* __restrict__ blockSums)
{
    __shared__ int s[256];
    int b = blockIdx.x, t = threadIdx.x;
    int base = b * SCAN_CHUNK + t * 4;
    int v0 = (base + 0 < N_NODES) ? counts[base + 0] : 0;
    int v1 = (base + 1 < N_NODES) ? counts[base + 1] : 0;
    int v2 = (base + 2 < N_NODES) ? counts[base + 2] : 0;
    int v3 = (base + 3 < N_NODES) ? counts[base + 3] : 0;
    int local = v0 + v1 + v2 + v3;
    s[t] = local;
    __syncthreads();
    for (int off = 1; off < 256; off <<= 1) {
        int x = (t >= off) ? s[t - off] : 0;
        __syncthreads();
        s[t] += x;
        __syncthreads();
    }
    int incl = s[t];
    int excl = incl - local;
    if (base + 0 < N_NODES) starts[base + 0] = excl;
    if (base + 1 < N_NODES) starts[base + 1] = excl + v0;
    if (base + 2 < N_NODES) starts[base + 2] = excl + v0 + v1;
    if (base + 3 < N_NODES) starts[base + 3] = excl + v0 + v1 + v2;
    if (t == 255) blockSums[b] = incl;
}

// scan2: exclusive scan of the (98) chunk totals, single block
__global__ __launch_bounds__(128) void scan2_kernel(int* __restrict__ blockSums)
{
    __shared__ int s[128];
    int t = threadIdx.x;
    int v = (t < SCAN_NB) ? blockSums[t] : 0;
    s[t] = v;
    __syncthreads();
    for (int off = 1; off < 128; off <<= 1) {
        int x = (t >= off) ? s[t - off] : 0;
        __syncthreads();
        s[t] += x;
        __syncthreads();
    }
    if (t < SCAN_NB) blockSums[t] = s[t] - v;   // exclusive
}

// scan3: add chunk offsets
__global__ __launch_bounds__(256) void scan3_kernel(
    int* __restrict__ starts, const int* __restrict__ blockSums)
{
    int i = blockIdx.x * 256 + threadIdx.x;
    if (i < N_NODES) starts[i] += blockSums[i >> 10];
}

__global__ __launch_bounds__(256) void scatter_kernel(
    const int* __restrict__ rows, const int* __restrict__ starts,
    int* __restrict__ cursor, int* __restrict__ edgeIds)
{
    int e = blockIdx.x * 256 + threadIdx.x;
    if (e >= E_EDGES) return;
    int r = rows[e];
    int pos = starts[r] + atomicAdd(&cursor[r], 1);
    edgeIds[pos] = e;
}

// ---------------------------------------------------------------------------
// Kernel C: CSR aggregation. 2 nodes per 256-thread block, thread = one dim.
// Single pass: out = (sum expAtt*V) / (sum expAtt + 1e-8). No atomics.
// ---------------------------------------------------------------------------
__global__ __launch_bounds__(256) void agg_csr_kernel(
    const float* __restrict__ V, const float* __restrict__ expAtt,
    const int* __restrict__ starts, const int* __restrict__ counts,
    const int* __restrict__ cols, const int* __restrict__ edgeIds,
    float* __restrict__ out)
{
    int t = threadIdx.x;
    int node = blockIdx.x * 2 + (t >> 7);
    int d = t & 127;
    if (node >= N_NODES) return;
    int h = d >> 5;

    int s   = starts[node];
    int cnt = counts[node];
    float norm = 0.f, acc = 0.f;
    for (int i = 0; i < cnt; ++i) {
        int eid = edgeIds[s + i];
        int c   = cols[eid];
        float w = expAtt[(size_t)eid * HEAD + h];
        norm += w;
        acc  += w * V[(size_t)c * 128 + d];
    }
    out[(size_t)node * 128 + d] = acc / (norm + 1e-8f);
}

// ---------------------------------------------------------------------------
extern "C" void kernel_launch(void* const* d_in, const int* in_sizes, int n_in,
                              void* d_out, int out_size, void* d_ws, size_t ws_size,
                              hipStream_t stream) {
    const float* embeds = (const float*)d_in[0];
    const float* qT     = (const float*)d_in[1];
    const float* kT     = (const float*)d_in[2];
    const float* vT     = (const float*)d_in[3];
    const float* filt   = (const float*)d_in[4];
    const int*   rows   = (const int*)d_in[5];
    const int*   cols   = (const int*)d_in[6];
    float*       out    = (float*)d_out;

    // Workspace layout:
    //   Q, K, V: N*128 f32 each | expAtt: E*4 f32 |
    //   counts, starts, cursor: N i32 | blockSums: 128 i32 | edgeIds: E i32
    float* Q      = (float*)d_ws;
    float* K      = Q + (size_t)N_NODES * 128;
    float* V      = K + (size_t)N_NODES * 128;
    float* expAtt = V + (size_t)N_NODES * 128;
    int* counts    = (int*)(expAtt + (size_t)E_EDGES * HEAD);
    int* starts    = counts + N_NODES;
    int* cursor    = starts + N_NODES;
    int* blockSums = cursor + N_NODES;
    int* edgeIds   = blockSums + 128;

    hipMemsetAsync(counts, 0, sizeof(int) * N_NODES, stream);
    hipMemsetAsync(cursor, 0, sizeof(int) * N_NODES, stream);

    qkv_kernel<<<(N_NODES + 63) / 64, 256, 0, stream>>>(embeds, qT, kT, vT, Q, K, V);

    hist_kernel<<<(E_EDGES + 255) / 256, 256, 0, stream>>>(rows, counts);
    scan1_kernel<<<SCAN_NB, 256, 0, stream>>>(counts, starts, blockSums);
    scan2_kernel<<<1, 128, 0, stream>>>(blockSums);
    scan3_kernel<<<(N_NODES + 255) / 256, 256, 0, stream>>>(starts, blockSums);
    scatter_kernel<<<(E_EDGES + 255) / 256, 256, 0, stream>>>(rows, starts, cursor, edgeIds);

    att_kernel<<<(E_EDGES * HEAD + 255) / 256, 256, 0, stream>>>(
        Q, K, filt, rows, cols, expAtt);

    agg_csr_kernel<<<(N_NODES + 1) / 2, 256, 0, stream>>>(
        V, expAtt, starts, counts, cols, edgeIds, out);
}

// Round 3
// 473.902 us; speedup vs baseline: 1.3299x; 1.2803x over previous
//
#include <hip/hip_runtime.h>

#define N_NODES 100000
#define E_EDGES 600000
#define LATDIM 128
#define HEAD 4
#define HDIM 32

#define SCAN_CHUNK 1024
#define SCAN_NB ((N_NODES + SCAN_CHUNK - 1) / SCAN_CHUNK)   // 98

// ---------------------------------------------------------------------------
// Kernel A: fused per-node Q/K/V transform.  out = embeds @ W for 3 weights.
// ---------------------------------------------------------------------------
__global__ __launch_bounds__(256) void qkv_kernel(
    const float* __restrict__ embeds,
    const float* __restrict__ qT,
    const float* __restrict__ kT,
    const float* __restrict__ vT,
    float* __restrict__ Q, float* __restrict__ K, float* __restrict__ V)
{
    __shared__ float smem[64][128];   // 32 KiB
    const int rowBase = blockIdx.x * 64;
    const int tid = threadIdx.x;

    for (int i = tid; i < 64 * 32; i += 256) {   // 2048 float4
        int r  = i >> 5;
        int c4 = i & 31;
        int gr = rowBase + r;
        float4 val = make_float4(0.f, 0.f, 0.f, 0.f);
        if (gr < N_NODES) val = ((const float4*)embeds)[gr * 32 + c4];
        ((float4*)&smem[r][0])[c4] = val;
    }
    __syncthreads();

    const int cg = tid & 31;
    const int rg = tid >> 5;

    const float* Ws[3]   = {qT, kT, vT};
    float*       Outs[3] = {Q, K, V};

    for (int w = 0; w < 3; ++w) {
        const float* __restrict__ W = Ws[w];
        float acc[8][4];
        #pragma unroll
        for (int i = 0; i < 8; ++i)
            #pragma unroll
            for (int j = 0; j < 4; ++j) acc[i][j] = 0.f;

        for (int k = 0; k < 128; ++k) {
            float4 wv = ((const float4*)(W + k * 128))[cg];
            #pragma unroll
            for (int i = 0; i < 8; ++i) {
                float e = smem[rg * 8 + i][k];
                acc[i][0] += e * wv.x;
                acc[i][1] += e * wv.y;
                acc[i][2] += e * wv.z;
                acc[i][3] += e * wv.w;
            }
        }

        float* __restrict__ O = Outs[w];
        #pragma unroll
        for (int i = 0; i < 8; ++i) {
            int gr = rowBase + rg * 8 + i;
            if (gr < N_NODES) {
                float4 v4 = make_float4(acc[i][0], acc[i][1], acc[i][2], acc[i][3]);
                ((float4*)(O + gr * 128))[cg] = v4;
            }
        }
    }
}

// ---------------------------------------------------------------------------
// CSR build: histogram -> exclusive scan -> scatter (stores COLS directly)
// ---------------------------------------------------------------------------
__global__ __launch_bounds__(256) void hist_kernel(
    const int* __restrict__ rows, int* __restrict__ counts)
{
    int e = blockIdx.x * 256 + threadIdx.x;
    if (e < E_EDGES) atomicAdd(&counts[rows[e]], 1);
}

__global__ __launch_bounds__(256) void scan1_kernel(
    const int* __restrict__ counts, int* __restrict__ starts,
    int* __restrict__ blockSums)
{
    __shared__ int s[256];
    int b = blockIdx.x, t = threadIdx.x;
    int base = b * SCAN_CHUNK + t * 4;
    int v0 = (base + 0 < N_NODES) ? counts[base + 0] : 0;
    int v1 = (base + 1 < N_NODES) ? counts[base + 1] : 0;
    int v2 = (base + 2 < N_NODES) ? counts[base + 2] : 0;
    int v3 = (base + 3 < N_NODES) ? counts[base + 3] : 0;
    int local = v0 + v1 + v2 + v3;
    s[t] = local;
    __syncthreads();
    for (int off = 1; off < 256; off <<= 1) {
        int x = (t >= off) ? s[t - off] : 0;
        __syncthreads();
        s[t] += x;
        __syncthreads();
    }
    int incl = s[t];
    int excl = incl - local;
    if (base + 0 < N_NODES) starts[base + 0] = excl;
    if (base + 1 < N_NODES) starts[base + 1] = excl + v0;
    if (base + 2 < N_NODES) starts[base + 2] = excl + v0 + v1;
    if (base + 3 < N_NODES) starts[base + 3] = excl + v0 + v1 + v2;
    if (t == 255) blockSums[b] = incl;
}

__global__ __launch_bounds__(128) void scan2_kernel(int* __restrict__ blockSums)
{
    __shared__ int s[128];
    int t = threadIdx.x;
    int v = (t < SCAN_NB) ? blockSums[t] : 0;
    s[t] = v;
    __syncthreads();
    for (int off = 1; off < 128; off <<= 1) {
        int x = (t >= off) ? s[t - off] : 0;
        __syncthreads();
        s[t] += x;
        __syncthreads();
    }
    if (t < SCAN_NB) blockSums[t] = s[t] - v;   // exclusive
}

// scan3: add chunk offsets; also init cursor = starts
__global__ __launch_bounds__(256) void scan3_kernel(
    int* __restrict__ starts, const int* __restrict__ blockSums,
    int* __restrict__ cursor)
{
    int i = blockIdx.x * 256 + threadIdx.x;
    if (i < N_NODES) {
        int v = starts[i] + blockSums[i >> 10];
        starts[i] = v;
        cursor[i] = v;
    }
}

__global__ __launch_bounds__(256) void scatter_kernel(
    const int* __restrict__ rows, const int* __restrict__ cols,
    int* __restrict__ cursor, int* __restrict__ csrCols)
{
    int e = blockIdx.x * 256 + threadIdx.x;
    if (e >= E_EDGES) return;
    int pos = atomicAdd(&cursor[rows[e]], 1);
    csrCols[pos] = cols[e];
}

// ---------------------------------------------------------------------------
// Kernel B: fused attention + aggregation over CSR. 2 nodes / 256-thr block,
// thread = one dim of one node. Head dot via __shfl_xor over the 32-lane
// head group (fully intra-wave -> no __syncthreads).
// ---------------------------------------------------------------------------
__global__ __launch_bounds__(256) void att_agg_kernel(
    const float* __restrict__ Q, const float* __restrict__ K,
    const float* __restrict__ V, const float* __restrict__ filt,
    const int* __restrict__ starts, const int* __restrict__ counts,
    const int* __restrict__ csrCols,
    float* __restrict__ out)
{
    int t = threadIdx.x;
    int node = blockIdx.x * 2 + (t >> 7);
    if (node >= N_NODES) return;
    int d = t & 127;
    int h = d >> 5;

    float qd  = Q[(size_t)node * 128 + d];
    int   s   = starts[node];
    int   cnt = counts[node];

    float norm = 0.f, acc = 0.f;
    int c = (cnt > 0) ? csrCols[s] : 0;
    for (int i = 0; i < cnt; ++i) {
        int cn = (i + 1 < cnt) ? csrCols[s + i + 1] : 0;   // prefetch next col
        float kd = K[(size_t)c * 128 + d];
        float vd = V[(size_t)c * 128 + d];
        float fl = filt[(size_t)c * HEAD + h];

        float p = qd * kd;
        p += __shfl_xor(p, 1);
        p += __shfl_xor(p, 2);
        p += __shfl_xor(p, 4);
        p += __shfl_xor(p, 8);
        p += __shfl_xor(p, 16);

        float logit = fminf(fmaxf(p, -10.f), 10.f) + fl;
        float w = __expf(logit);
        norm += w;
        acc  += w * vd;
        c = cn;
    }
    out[(size_t)node * 128 + d] = acc / (norm + 1e-8f);
}

// ---------------------------------------------------------------------------
extern "C" void kernel_launch(void* const* d_in, const int* in_sizes, int n_in,
                              void* d_out, int out_size, void* d_ws, size_t ws_size,
                              hipStream_t stream) {
    const float* embeds = (const float*)d_in[0];
    const float* qT     = (const float*)d_in[1];
    const float* kT     = (const float*)d_in[2];
    const float* vT     = (const float*)d_in[3];
    const float* filt   = (const float*)d_in[4];
    const int*   rows   = (const int*)d_in[5];
    const int*   cols   = (const int*)d_in[6];
    float*       out    = (float*)d_out;

    // Workspace: Q,K,V: N*128 f32 | counts,starts,cursor: N i32 |
    //            blockSums: 128 i32 | csrCols: E i32
    float* Q      = (float*)d_ws;
    float* K      = Q + (size_t)N_NODES * 128;
    float* V      = K + (size_t)N_NODES * 128;
    int* counts    = (int*)(V + (size_t)N_NODES * 128);
    int* starts    = counts + N_NODES;
    int* cursor    = starts + N_NODES;
    int* blockSums = cursor + N_NODES;
    int* csrCols   = blockSums + 128;

    hipMemsetAsync(counts, 0, sizeof(int) * N_NODES, stream);

    qkv_kernel<<<(N_NODES + 63) / 64, 256, 0, stream>>>(embeds, qT, kT, vT, Q, K, V);

    hist_kernel<<<(E_EDGES + 255) / 256, 256, 0, stream>>>(rows, counts);
    scan1_kernel<<<SCAN_NB, 256, 0, stream>>>(counts, starts, blockSums);
    scan2_kernel<<<1, 128, 0, stream>>>(blockSums);
    scan3_kernel<<<(N_NODES + 255) / 256, 256, 0, stream>>>(starts, blockSums, cursor);
    scatter_kernel<<<(E_EDGES + 255) / 256, 256, 0, stream>>>(rows, cols, cursor, csrCols);

    att_agg_kernel<<<(N_NODES + 1) / 2, 256, 0, stream>>>(
        Q, K, V, filt, starts, counts, csrCols, out);
}

// Round 4
// 418.675 us; speedup vs baseline: 1.5053x; 1.1319x over previous
//
#include <hip/hip_runtime.h>

#define N_NODES 100000
#define E_EDGES 600000
#define LATDIM 128
#define HEAD 4
#define HDIM 32

#define SCAN_CHUNK 1024
#define SCAN_NB ((N_NODES + SCAN_CHUNK - 1) / SCAN_CHUNK)   // 98

__device__ __forceinline__ unsigned f32_to_bf16_rne(float x) {
    unsigned u = __float_as_uint(x);
    u += 0x7fffu + ((u >> 16) & 1u);   // round to nearest even
    return u >> 16;
}

// ---------------------------------------------------------------------------
// Kernel A: fused per-node Q/K/V transform.
//   Q written f32; K,V packed as bf16 pair into one uint per (node, dim).
// ---------------------------------------------------------------------------
__global__ __launch_bounds__(256) void qkv_kernel(
    const float* __restrict__ embeds,
    const float* __restrict__ qT,
    const float* __restrict__ kT,
    const float* __restrict__ vT,
    float* __restrict__ Q, unsigned* __restrict__ KV)
{
    __shared__ float smem[64][128];   // 32 KiB
    const int rowBase = blockIdx.x * 64;
    const int tid = threadIdx.x;

    for (int i = tid; i < 64 * 32; i += 256) {   // 2048 float4
        int r  = i >> 5;
        int c4 = i & 31;
        int gr = rowBase + r;
        float4 val = make_float4(0.f, 0.f, 0.f, 0.f);
        if (gr < N_NODES) val = ((const float4*)embeds)[gr * 32 + c4];
        ((float4*)&smem[r][0])[c4] = val;
    }
    __syncthreads();

    const int cg = tid & 31;      // col group (4 cols)
    const int rg = tid >> 5;      // row group (8 rows)

    float acc[8][4];
    float kacc[8][4];

    // ---- Q pass ----
    #pragma unroll
    for (int i = 0; i < 8; ++i)
        #pragma unroll
        for (int j = 0; j < 4; ++j) acc[i][j] = 0.f;
    for (int k = 0; k < 128; ++k) {
        float4 wv = ((const float4*)(qT + k * 128))[cg];
        #pragma unroll
        for (int i = 0; i < 8; ++i) {
            float e = smem[rg * 8 + i][k];
            acc[i][0] += e * wv.x;
            acc[i][1] += e * wv.y;
            acc[i][2] += e * wv.z;
            acc[i][3] += e * wv.w;
        }
    }
    #pragma unroll
    for (int i = 0; i < 8; ++i) {
        int gr = rowBase + rg * 8 + i;
        if (gr < N_NODES)
            ((float4*)(Q + (size_t)gr * 128))[cg] =
                make_float4(acc[i][0], acc[i][1], acc[i][2], acc[i][3]);
    }

    // ---- K pass (keep in kacc) ----
    #pragma unroll
    for (int i = 0; i < 8; ++i)
        #pragma unroll
        for (int j = 0; j < 4; ++j) kacc[i][j] = 0.f;
    for (int k = 0; k < 128; ++k) {
        float4 wv = ((const float4*)(kT + k * 128))[cg];
        #pragma unroll
        for (int i = 0; i < 8; ++i) {
            float e = smem[rg * 8 + i][k];
            kacc[i][0] += e * wv.x;
            kacc[i][1] += e * wv.y;
            kacc[i][2] += e * wv.z;
            kacc[i][3] += e * wv.w;
        }
    }

    // ---- V pass, then pack (k,v) -> uint ----
    #pragma unroll
    for (int i = 0; i < 8; ++i)
        #pragma unroll
        for (int j = 0; j < 4; ++j) acc[i][j] = 0.f;
    for (int k = 0; k < 128; ++k) {
        float4 wv = ((const float4*)(vT + k * 128))[cg];
        #pragma unroll
        for (int i = 0; i < 8; ++i) {
            float e = smem[rg * 8 + i][k];
            acc[i][0] += e * wv.x;
            acc[i][1] += e * wv.y;
            acc[i][2] += e * wv.z;
            acc[i][3] += e * wv.w;
        }
    }
    #pragma unroll
    for (int i = 0; i < 8; ++i) {
        int gr = rowBase + rg * 8 + i;
        if (gr < N_NODES) {
            uint4 p;
            p.x = f32_to_bf16_rne(kacc[i][0]) | (f32_to_bf16_rne(acc[i][0]) << 16);
            p.y = f32_to_bf16_rne(kacc[i][1]) | (f32_to_bf16_rne(acc[i][1]) << 16);
            p.z = f32_to_bf16_rne(kacc[i][2]) | (f32_to_bf16_rne(acc[i][2]) << 16);
            p.w = f32_to_bf16_rne(kacc[i][3]) | (f32_to_bf16_rne(acc[i][3]) << 16);
            ((uint4*)(KV + (size_t)gr * 128))[cg] = p;
        }
    }
}

// ---------------------------------------------------------------------------
// CSR build: histogram -> exclusive scan -> scatter (stores COLS directly)
// ---------------------------------------------------------------------------
__global__ __launch_bounds__(256) void hist_kernel(
    const int* __restrict__ rows, int* __restrict__ counts)
{
    int e = blockIdx.x * 256 + threadIdx.x;
    if (e < E_EDGES) atomicAdd(&counts[rows[e]], 1);
}

__global__ __launch_bounds__(256) void scan1_kernel(
    const int* __restrict__ counts, int* __restrict__ starts,
    int* __restrict__ blockSums)
{
    __shared__ int s[256];
    int b = blockIdx.x, t = threadIdx.x;
    int base = b * SCAN_CHUNK + t * 4;
    int v0 = (base + 0 < N_NODES) ? counts[base + 0] : 0;
    int v1 = (base + 1 < N_NODES) ? counts[base + 1] : 0;
    int v2 = (base + 2 < N_NODES) ? counts[base + 2] : 0;
    int v3 = (base + 3 < N_NODES) ? counts[base + 3] : 0;
    int local = v0 + v1 + v2 + v3;
    s[t] = local;
    __syncthreads();
    for (int off = 1; off < 256; off <<= 1) {
        int x = (t >= off) ? s[t - off] : 0;
        __syncthreads();
        s[t] += x;
        __syncthreads();
    }
    int incl = s[t];
    int excl = incl - local;
    if (base + 0 < N_NODES) starts[base + 0] = excl;
    if (base + 1 < N_NODES) starts[base + 1] = excl + v0;
    if (base + 2 < N_NODES) starts[base + 2] = excl + v0 + v1;
    if (base + 3 < N_NODES) starts[base + 3] = excl + v0 + v1 + v2;
    if (t == 255) blockSums[b] = incl;
}

__global__ __launch_bounds__(128) void scan2_kernel(int* __restrict__ blockSums)
{
    __shared__ int s[128];
    int t = threadIdx.x;
    int v = (t < SCAN_NB) ? blockSums[t] : 0;
    s[t] = v;
    __syncthreads();
    for (int off = 1; off < 128; off <<= 1) {
        int x = (t >= off) ? s[t - off] : 0;
        __syncthreads();
        s[t] += x;
        __syncthreads();
    }
    if (t < SCAN_NB) blockSums[t] = s[t] - v;   // exclusive
}

__global__ __launch_bounds__(256) void scan3_kernel(
    int* __restrict__ starts, const int* __restrict__ blockSums,
    int* __restrict__ cursor)
{
    int i = blockIdx.x * 256 + threadIdx.x;
    if (i < N_NODES) {
        int v = starts[i] + blockSums[i >> 10];
        starts[i] = v;
        cursor[i] = v;
    }
}

__global__ __launch_bounds__(256) void scatter_kernel(
    const int* __restrict__ rows, const int* __restrict__ cols,
    int* __restrict__ cursor, int* __restrict__ csrCols)
{
    int e = blockIdx.x * 256 + threadIdx.x;
    if (e >= E_EDGES) return;
    int pos = atomicAdd(&cursor[rows[e]], 1);
    csrCols[pos] = cols[e];
}

// ---------------------------------------------------------------------------
// Kernel B: fused attention + aggregation, bf16-packed K/V, 2-edge unroll.
// 2 nodes / 256-thr block, thread = one dim. Head dot via __shfl_xor over
// the 32-lane head group (intra-wave, no __syncthreads).
// ---------------------------------------------------------------------------
__global__ __launch_bounds__(256) void att_agg_kernel(
    const float* __restrict__ Q, const unsigned* __restrict__ KV,
    const float* __restrict__ filt,
    const int* __restrict__ starts, const int* __restrict__ counts,
    const int* __restrict__ csrCols,
    float* __restrict__ out)
{
    int t = threadIdx.x;
    int node = blockIdx.x * 2 + (t >> 7);
    if (node >= N_NODES) return;
    int d = t & 127;
    int h = d >> 5;

    float qd  = Q[(size_t)node * 128 + d];
    int   s   = starts[node];
    int   cnt = counts[node];

    float norm = 0.f, acc = 0.f;
    int i = 0;
    for (; i + 2 <= cnt; i += 2) {
        int c0 = csrCols[s + i];
        int c1 = csrCols[s + i + 1];
        unsigned kv0 = KV[(size_t)c0 * 128 + d];
        unsigned kv1 = KV[(size_t)c1 * 128 + d];
        float f0 = filt[(size_t)c0 * HEAD + h];
        float f1 = filt[(size_t)c1 * HEAD + h];
        float k0 = __uint_as_float(kv0 << 16);
        float v0 = __uint_as_float(kv0 & 0xffff0000u);
        float k1 = __uint_as_float(kv1 << 16);
        float v1 = __uint_as_float(kv1 & 0xffff0000u);

        float p0 = qd * k0;
        float p1 = qd * k1;
        p0 += __shfl_xor(p0, 1);   p1 += __shfl_xor(p1, 1);
        p0 += __shfl_xor(p0, 2);   p1 += __shfl_xor(p1, 2);
        p0 += __shfl_xor(p0, 4);   p1 += __shfl_xor(p1, 4);
        p0 += __shfl_xor(p0, 8);   p1 += __shfl_xor(p1, 8);
        p0 += __shfl_xor(p0, 16);  p1 += __shfl_xor(p1, 16);

        float w0 = __expf(fminf(fmaxf(p0, -10.f), 10.f) + f0);
        float w1 = __expf(fminf(fmaxf(p1, -10.f), 10.f) + f1);
        norm += w0 + w1;
        acc  += w0 * v0 + w1 * v1;
    }
    if (i < cnt) {
        int c0 = csrCols[s + i];
        unsigned kv0 = KV[(size_t)c0 * 128 + d];
        float f0 = filt[(size_t)c0 * HEAD + h];
        float k0 = __uint_as_float(kv0 << 16);
        float v0 = __uint_as_float(kv0 & 0xffff0000u);
        float p0 = qd * k0;
        p0 += __shfl_xor(p0, 1);
        p0 += __shfl_xor(p0, 2);
        p0 += __shfl_xor(p0, 4);
        p0 += __shfl_xor(p0, 8);
        p0 += __shfl_xor(p0, 16);
        float w0 = __expf(fminf(fmaxf(p0, -10.f), 10.f) + f0);
        norm += w0;
        acc  += w0 * v0;
    }
    out[(size_t)node * 128 + d] = acc / (norm + 1e-8f);
}

// ---------------------------------------------------------------------------
extern "C" void kernel_launch(void* const* d_in, const int* in_sizes, int n_in,
                              void* d_out, int out_size, void* d_ws, size_t ws_size,
                              hipStream_t stream) {
    const float* embeds = (const float*)d_in[0];
    const float* qT     = (const float*)d_in[1];
    const float* kT     = (const float*)d_in[2];
    const float* vT     = (const float*)d_in[3];
    const float* filt   = (const float*)d_in[4];
    const int*   rows   = (const int*)d_in[5];
    const int*   cols   = (const int*)d_in[6];
    float*       out    = (float*)d_out;

    // Workspace: Q: N*128 f32 | KV: N*128 u32 | counts,starts,cursor: N i32 |
    //            blockSums: 128 i32 | csrCols: E i32
    float*    Q  = (float*)d_ws;
    unsigned* KV = (unsigned*)(Q + (size_t)N_NODES * 128);
    int* counts    = (int*)(KV + (size_t)N_NODES * 128);
    int* starts    = counts + N_NODES;
    int* cursor    = starts + N_NODES;
    int* blockSums = cursor + N_NODES;
    int* csrCols   = blockSums + 128;

    hipMemsetAsync(counts, 0, sizeof(int) * N_NODES, stream);

    qkv_kernel<<<(N_NODES + 63) / 64, 256, 0, stream>>>(embeds, qT, kT, vT, Q, KV);

    hist_kernel<<<(E_EDGES + 255) / 256, 256, 0, stream>>>(rows, counts);
    scan1_kernel<<<SCAN_NB, 256, 0, stream>>>(counts, starts, blockSums);
    scan2_kernel<<<1, 128, 0, stream>>>(blockSums);
    scan3_kernel<<<(N_NODES + 255) / 256, 256, 0, stream>>>(starts, blockSums, cursor);
    scatter_kernel<<<(E_EDGES + 255) / 256, 256, 0, stream>>>(rows, cols, cursor, csrCols);

    att_agg_kernel<<<(N_NODES + 1) / 2, 256, 0, stream>>>(
        Q, KV, filt, starts, counts, csrCols, out);
}